// Round 3
// baseline (79.138 us; speedup 1.0000x reference)
//
#include <hip/hip_runtime.h>
#include <hip/hip_bf16.h>

typedef __bf16 bf16x8 __attribute__((ext_vector_type(8)));
typedef float f32x4 __attribute__((ext_vector_type(4)));

#define NB 8
#define NH 128
#define NWID 128
#define NC 32
#define NO 32
#define NPTS 9
#define KPAD 296      // sW row stride in halves: 148 words -> near-conflict-free
#define PB 64         // pixels per block (4 waves x 16)

__global__ __launch_bounds__(256, 4)
void dcn_kernel(const float* __restrict__ x,
                const float* __restrict__ off,
                const float* __restrict__ Wsrc,
                const float* __restrict__ bias,
                float* __restrict__ out)
{
    __shared__ __hip_bfloat16 sW[NO][KPAD];

    const int tid = threadIdx.x;

    // ---- stage W: W[n][c][o] -> sW[o][n*32+c] (bf16) ----
    for (int idx = tid; idx < NPTS * NC * NO; idx += 256) {
        int n = idx >> 10;        // /(NC*NO)
        int r = idx & 1023;
        int c = r >> 5;
        int o = r & 31;
        sW[o][(n << 5) + c] = __float2bfloat16(Wsrc[idx]);
    }
    __syncthreads();

    const int wave = tid >> 6;
    const int lane = tid & 63;
    const int row  = lane & 15;   // pixel within wave tile == A-frag row == B col
    const int cq   = lane >> 4;   // channel quad: channels 8cq..8cq+7 (A-frag k group)
    const int pix0 = blockIdx.x * PB;
    const int gp   = pix0 + (wave << 4) + row;
    const int bidx = gp >> 14;
    const int hh   = (gp >> 7) & 127;
    const int ww   = gp & 127;
    const float* xb = x + ((size_t)bidx << 19);   // batch base
    const float* xc = xb + (cq << 3);             // + channel base for this lane
    const float* offp = off + (size_t)gp * 18;

    // TF-quirk init_off: stack([ii,jj]).reshape(-1,2) pairs ACROSS the ii/jj boundary:
    // (0,0),(0,1),(1,1),(2,2),(2,0),(1,2),(0,1),(2,0),(1,2)
    const int ioff0[9] = {0,0,1,2,2,1,0,2,1};
    const int ioff1[9] = {0,1,1,2,0,2,1,0,2};

    float2 ov[9];
    #pragma unroll
    for (int n = 0; n < 9; ++n)
        ov[n] = *reinterpret_cast<const float2*>(offp + 2 * n);

    f32x4 acc0 = {0.f, 0.f, 0.f, 0.f};
    f32x4 acc1 = {0.f, 0.f, 0.f, 0.f};

    #pragma unroll
    for (int n = 0; n < 9; ++n) {
        float c0 = fminf(fmaxf((float)(hh - 1 + ioff0[n]) + ov[n].x, 0.f), 127.f);
        float c1 = fminf(fmaxf((float)(ww - 1 + ioff1[n]) + ov[n].y, 0.f), 127.f);
        float fl0 = floorf(c0), fl1 = floorf(c1);
        int lt0 = (int)fl0, lt1 = (int)fl1;
        int rb0 = (int)ceilf(c0), rb1 = (int)ceilf(c1);
        float f0 = c0 - fl0, f1 = c1 - fl1;

        const float* p_lt = xc + (((lt0 << 7) + lt1) << 5);
        const float* p_rt = xc + (((rb0 << 7) + lt1) << 5);
        const float* p_lb = xc + (((lt0 << 7) + rb1) << 5);
        const float* p_rb = xc + (((rb0 << 7) + rb1) << 5);
        f32x4 lt_a = *(const f32x4*)p_lt, lt_b = *(const f32x4*)(p_lt + 4);
        f32x4 rt_a = *(const f32x4*)p_rt, rt_b = *(const f32x4*)(p_rt + 4);
        f32x4 lb_a = *(const f32x4*)p_lb, lb_b = *(const f32x4*)(p_lb + 4);
        f32x4 rb_a = *(const f32x4*)p_rb, rb_b = *(const f32x4*)(p_rb + 4);

        union { bf16x8 v; __hip_bfloat16 h[8]; } au;
        #pragma unroll
        for (int j = 0; j < 4; ++j) {
            float t = lt_a[j] + (rt_a[j] - lt_a[j]) * f0;
            float b = lb_a[j] + (rb_a[j] - lb_a[j]) * f0;
            au.h[j] = __float2bfloat16(t + (b - t) * f1);
        }
        #pragma unroll
        for (int j = 0; j < 4; ++j) {
            float t = lt_b[j] + (rt_b[j] - lt_b[j]) * f0;
            float b = lb_b[j] + (rb_b[j] - lb_b[j]) * f0;
            au.h[4 + j] = __float2bfloat16(t + (b - t) * f1);
        }

        const int kk = (n << 5) + (cq << 3);
        bf16x8 b0 = *reinterpret_cast<const bf16x8*>(&sW[row][kk]);
        bf16x8 b1 = *reinterpret_cast<const bf16x8*>(&sW[row + 16][kk]);
        acc0 = __builtin_amdgcn_mfma_f32_16x16x32_bf16(au.v, b0, acc0, 0, 0, 0);
        acc1 = __builtin_amdgcn_mfma_f32_16x16x32_bf16(au.v, b1, acc1, 0, 0, 0);
    }

    // ---- epilogue: C/D layout col=lane&15, row=(lane>>4)*4+i ----
    const float bias0 = bias[row];
    const float bias1 = bias[row + 16];
    const int rbase = (wave << 4) + (cq << 2);
    #pragma unroll
    for (int i = 0; i < 4; ++i) {
        float* op = out + (size_t)(pix0 + rbase + i) * NO;
        op[row]      = acc0[i] + bias0;
        op[row + 16] = acc1[i] + bias1;
    }
}

extern "C" void kernel_launch(void* const* d_in, const int* in_sizes, int n_in,
                              void* d_out, int out_size, void* d_ws, size_t ws_size,
                              hipStream_t stream) {
    const float* x    = (const float*)d_in[0];
    const float* off  = (const float*)d_in[1];
    const float* Wsrc = (const float*)d_in[2];
    const float* bias = (const float*)d_in[3];
    float* out = (float*)d_out;
    const int npix = NB * NH * NWID;          // 131072
    dcn_kernel<<<npix / PB, 256, 0, stream>>>(x, off, Wsrc, bias, out);
}

// Round 4
// 77.596 us; speedup vs baseline: 1.0199x; 1.0199x over previous
//
#include <hip/hip_runtime.h>
#include <hip/hip_bf16.h>

typedef __bf16 bf16x8 __attribute__((ext_vector_type(8)));
typedef float f32x4 __attribute__((ext_vector_type(4)));

#define NB 8
#define NH 128
#define NWID 128
#define NC 32
#define NO 32
#define NPTS 9
#define KPAD 296      // sW row stride in halves
#define PB 64         // pixels per block (4 waves x 16)

__global__ __launch_bounds__(256, 2)
void dcn_kernel(const float* __restrict__ x,
                const float* __restrict__ off,
                const float* __restrict__ Wsrc,
                const float* __restrict__ bias,
                float* __restrict__ out)
{
    __shared__ __hip_bfloat16 sW[NO][KPAD];

    const int tid = threadIdx.x;

    // ---- stage W: W[n][c][o] -> sW[o][n*32+c] (bf16) ----
    for (int idx = tid; idx < NPTS * NC * NO; idx += 256) {
        int n = idx >> 10;        // /(NC*NO)
        int r = idx & 1023;
        int c = r >> 5;
        int o = r & 31;
        sW[o][(n << 5) + c] = __float2bfloat16(Wsrc[idx]);
    }
    __syncthreads();

    // XCD swizzle: grid = 2048 = 8 XCDs x 256 blocks; 256 blocks == one batch
    // image (2.1 MB of x < 4 MiB L2). HW assigns XCD ~ blockIdx%8, so make all
    // blocks of one image share an XCD -> gathers are L2-resident.
    const int lb = ((blockIdx.x & 7) << 8) | (blockIdx.x >> 3);
    const int pix0 = lb * PB;

    const int wave = tid >> 6;
    const int lane = tid & 63;
    const int row  = lane & 15;   // pixel within wave tile == A-frag row == B col
    const int cq   = lane >> 4;   // channel quad: channels 8cq..8cq+7 (A-frag k group)
    const int gp   = pix0 + (wave << 4) + row;
    const int bidx = gp >> 14;
    const int hh   = (gp >> 7) & 127;
    const int ww   = gp & 127;
    const float* xb = x + ((size_t)bidx << 19);   // batch base
    const float* xc = xb + (cq << 3);             // + channel base for this lane
    const float* offp = off + (size_t)gp * 18;

    // TF-quirk init_off: stack([ii,jj]).reshape(-1,2) pairs ACROSS the ii/jj boundary:
    // (0,0),(0,1),(1,1),(2,2),(2,0),(1,2),(0,1),(2,0),(1,2)
    const int ioff0[9] = {0,0,1,2,2,1,0,2,1};
    const int ioff1[9] = {0,1,1,2,0,2,1,0,2};

    float2 ov[9];
    #pragma unroll
    for (int n = 0; n < 9; ++n)
        ov[n] = *reinterpret_cast<const float2*>(offp + 2 * n);

    f32x4 acc0 = {0.f, 0.f, 0.f, 0.f};
    f32x4 acc1 = {0.f, 0.f, 0.f, 0.f};

    #pragma unroll
    for (int n = 0; n < 9; ++n) {
        float c0 = fminf(fmaxf((float)(hh - 1 + ioff0[n]) + ov[n].x, 0.f), 127.f);
        float c1 = fminf(fmaxf((float)(ww - 1 + ioff1[n]) + ov[n].y, 0.f), 127.f);
        float fl0 = floorf(c0), fl1 = floorf(c1);
        int lt0 = (int)fl0, lt1 = (int)fl1;
        int rb0 = (int)ceilf(c0), rb1 = (int)ceilf(c1);
        float f0 = c0 - fl0, f1 = c1 - fl1;

        const float* p_lt = xc + (((lt0 << 7) + lt1) << 5);
        const float* p_rt = xc + (((rb0 << 7) + lt1) << 5);
        const float* p_lb = xc + (((lt0 << 7) + rb1) << 5);
        const float* p_rb = xc + (((rb0 << 7) + rb1) << 5);
        f32x4 lt_a = *(const f32x4*)p_lt, lt_b = *(const f32x4*)(p_lt + 4);
        f32x4 rt_a = *(const f32x4*)p_rt, rt_b = *(const f32x4*)(p_rt + 4);
        f32x4 lb_a = *(const f32x4*)p_lb, lb_b = *(const f32x4*)(p_lb + 4);
        f32x4 rb_a = *(const f32x4*)p_rb, rb_b = *(const f32x4*)(p_rb + 4);

        union { bf16x8 v; __hip_bfloat16 h[8]; } au;
        #pragma unroll
        for (int j = 0; j < 4; ++j) {
            float t = lt_a[j] + (rt_a[j] - lt_a[j]) * f0;
            float b = lb_a[j] + (rb_a[j] - lb_a[j]) * f0;
            au.h[j] = __float2bfloat16(t + (b - t) * f1);
        }
        #pragma unroll
        for (int j = 0; j < 4; ++j) {
            float t = lt_b[j] + (rt_b[j] - lt_b[j]) * f0;
            float b = lb_b[j] + (rb_b[j] - lb_b[j]) * f0;
            au.h[4 + j] = __float2bfloat16(t + (b - t) * f1);
        }

        const int kk = (n << 5) + (cq << 3);
        bf16x8 b0 = *reinterpret_cast<const bf16x8*>(&sW[row][kk]);
        bf16x8 b1 = *reinterpret_cast<const bf16x8*>(&sW[row + 16][kk]);
        acc0 = __builtin_amdgcn_mfma_f32_16x16x32_bf16(au.v, b0, acc0, 0, 0, 0);
        acc1 = __builtin_amdgcn_mfma_f32_16x16x32_bf16(au.v, b1, acc1, 0, 0, 0);
    }

    // ---- epilogue: C/D layout col=lane&15, row=(lane>>4)*4+i ----
    const float bias0 = bias[row];
    const float bias1 = bias[row + 16];
    const int rbase = (wave << 4) + (cq << 2);
    #pragma unroll
    for (int i = 0; i < 4; ++i) {
        float* op = out + (size_t)(pix0 + rbase + i) * NO;
        op[row]      = acc0[i] + bias0;
        op[row + 16] = acc1[i] + bias1;
    }
}

extern "C" void kernel_launch(void* const* d_in, const int* in_sizes, int n_in,
                              void* d_out, int out_size, void* d_ws, size_t ws_size,
                              hipStream_t stream) {
    const float* x    = (const float*)d_in[0];
    const float* off  = (const float*)d_in[1];
    const float* Wsrc = (const float*)d_in[2];
    const float* bias = (const float*)d_in[3];
    float* out = (float*)d_out;
    const int npix = NB * NH * NWID;          // 131072
    dcn_kernel<<<npix / PB, 256, 0, stream>>>(x, off, Wsrc, bias, out);
}

// Round 6
// 72.028 us; speedup vs baseline: 1.0987x; 1.0773x over previous
//
#include <hip/hip_runtime.h>
#include <hip/hip_bf16.h>

typedef __bf16 bf16x8 __attribute__((ext_vector_type(8)));
typedef float f32x4 __attribute__((ext_vector_type(4)));

#define NB 8
#define NH 128
#define NWID 128
#define NC 32
#define NO 32
#define NPTS 9
#define KPAD 296      // sW row stride in halves
#define PB 64         // pixels per block (4 waves x 16)

__global__ __launch_bounds__(256, 2)
void dcn_kernel(const float* __restrict__ x,
                const float* __restrict__ off,
                const float* __restrict__ Wsrc,
                const float* __restrict__ bias,
                float* __restrict__ out)
{
    __shared__ __hip_bfloat16 sW[NO][KPAD];

    const int tid = threadIdx.x;

    // ---- stage W (identity layout, R4-verified): W[n][c][o] -> sW[o][n*32+c] ----
    for (int idx = tid; idx < NPTS * NC * NO; idx += 256) {
        int n = idx >> 10;        // /(NC*NO)
        int r = idx & 1023;
        int c = r >> 5;
        int o = r & 31;
        sW[o][(n << 5) + c] = __float2bfloat16(Wsrc[idx]);
    }
    __syncthreads();

    // XCD swizzle: grid 2048 = 8 XCDs x 256 blocks; 256 blocks == one image
    // (2.1 MB < 4 MiB L2) -> gathers L2-resident per XCD. (R4: FETCH 110->13MB)
    const int lb = ((blockIdx.x & 7) << 8) | (blockIdx.x >> 3);
    const int pix0 = lb * PB;

    const int wave = tid >> 6;
    const int lane = tid & 63;
    const int row  = lane & 15;   // pixel within wave tile == A-frag row == B col
    const int cq   = lane >> 4;   // channel quad: channels 8cq..8cq+7
    const int gp   = pix0 + (wave << 4) + row;
    const int bidx = gp >> 14;
    const int hh   = (gp >> 7) & 127;
    const int ww   = gp & 127;
    const float* xb = x + ((size_t)bidx << 19);
    const float* xc = xb + (cq << 3);             // channel base (R4-verified)
    const float* offp = off + (size_t)gp * 18;

    // TF-quirk init_off: stack([ii,jj]).reshape(-1,2) pairs ACROSS the ii/jj boundary
    const int ioff0[9] = {0,0,1,2,2,1,0,2,1};
    const int ioff1[9] = {0,1,1,2,0,2,1,0,2};

    float2 ov[9];
    #pragma unroll
    for (int n = 0; n < 9; ++n)
        ov[n] = *reinterpret_cast<const float2*>(offp + 2 * n);

    f32x4 acc0 = {0.f, 0.f, 0.f, 0.f};
    f32x4 acc1 = {0.f, 0.f, 0.f, 0.f};

    // depth-2 software pipeline over the 9 points:
    // slot layout: [lt_a, lt_b, rt_a, rt_b, lb_a, lb_b, rb_a, rb_b]
    f32x4 L[2][8];
    float ff0[2], ff1[2];

#define ISSUE(S, N) {                                                          \
        float c0 = fminf(fmaxf((float)(hh - 1 + ioff0[N]) + ov[N].x, 0.f), 127.f); \
        float c1 = fminf(fmaxf((float)(ww - 1 + ioff1[N]) + ov[N].y, 0.f), 127.f); \
        float fl0 = floorf(c0), fl1 = floorf(c1);                              \
        int lt0 = (int)fl0, lt1 = (int)fl1;                                    \
        int rb0 = (int)ceilf(c0), rb1 = (int)ceilf(c1);                        \
        ff0[S] = c0 - fl0; ff1[S] = c1 - fl1;                                  \
        const float* p_lt = xc + ((((lt0 << 7) + lt1)) << 5);                  \
        const float* p_rt = xc + ((((rb0 << 7) + lt1)) << 5);                  \
        const float* p_lb = xc + ((((lt0 << 7) + rb1)) << 5);                  \
        const float* p_rb = xc + ((((rb0 << 7) + rb1)) << 5);                  \
        L[S][0] = *(const f32x4*)p_lt; L[S][1] = *(const f32x4*)(p_lt + 4);    \
        L[S][2] = *(const f32x4*)p_rt; L[S][3] = *(const f32x4*)(p_rt + 4);    \
        L[S][4] = *(const f32x4*)p_lb; L[S][5] = *(const f32x4*)(p_lb + 4);    \
        L[S][6] = *(const f32x4*)p_rb; L[S][7] = *(const f32x4*)(p_rb + 4);    \
    }

#define CONSUME(S, N) {                                                        \
        float f0 = ff0[S], f1 = ff1[S];                                        \
        union { bf16x8 v; __hip_bfloat16 h[8]; } au;                           \
        _Pragma("unroll")                                                      \
        for (int j = 0; j < 4; ++j) {                                          \
            float t = L[S][0][j] + (L[S][2][j] - L[S][0][j]) * f0;             \
            float b = L[S][4][j] + (L[S][6][j] - L[S][4][j]) * f0;             \
            au.h[j] = __float2bfloat16(t + (b - t) * f1);                      \
        }                                                                      \
        _Pragma("unroll")                                                      \
        for (int j = 0; j < 4; ++j) {                                          \
            float t = L[S][1][j] + (L[S][3][j] - L[S][1][j]) * f0;             \
            float b = L[S][5][j] + (L[S][7][j] - L[S][5][j]) * f0;             \
            au.h[4 + j] = __float2bfloat16(t + (b - t) * f1);                  \
        }                                                                      \
        const int kk = ((N) << 5) + (cq << 3);                                 \
        bf16x8 b0 = *reinterpret_cast<const bf16x8*>(&sW[row][kk]);            \
        bf16x8 b1 = *reinterpret_cast<const bf16x8*>(&sW[row + 16][kk]);       \
        acc0 = __builtin_amdgcn_mfma_f32_16x16x32_bf16(au.v, b0, acc0, 0, 0, 0); \
        acc1 = __builtin_amdgcn_mfma_f32_16x16x32_bf16(au.v, b1, acc1, 0, 0, 0); \
    }

    ISSUE(0, 0)
    #pragma unroll
    for (int n = 0; n < 9; ++n) {
        if (n < 8) ISSUE((n + 1) & 1, n + 1)
        // pin: next point's 8 loads must stay issued ABOVE this point's consume
        __builtin_amdgcn_sched_barrier(0);
        CONSUME(n & 1, n)
    }
#undef ISSUE
#undef CONSUME

    // ---- epilogue: C/D layout col=lane&15, row=(lane>>4)*4+i (R4-verified) ----
    const float bias0 = bias[row];
    const float bias1 = bias[row + 16];
    const int rbase = (wave << 4) + (cq << 2);
    #pragma unroll
    for (int i = 0; i < 4; ++i) {
        float* op = out + (size_t)(pix0 + rbase + i) * NO;
        op[row]      = acc0[i] + bias0;
        op[row + 16] = acc1[i] + bias1;
    }
}

extern "C" void kernel_launch(void* const* d_in, const int* in_sizes, int n_in,
                              void* d_out, int out_size, void* d_ws, size_t ws_size,
                              hipStream_t stream) {
    const float* x    = (const float*)d_in[0];
    const float* off  = (const float*)d_in[1];
    const float* Wsrc = (const float*)d_in[2];
    const float* bias = (const float*)d_in[3];
    float* out = (float*)d_out;
    const int npix = NB * NH * NWID;          // 131072
    dcn_kernel<<<npix / PB, 256, 0, stream>>>(x, off, Wsrc, bias, out);
}